// Round 10
// baseline (1775.505 us; speedup 1.0000x reference)
//
#include <hip/hip_runtime.h>

// ConvLSTM B=8,T=16,CIN=16,HID=64,H=W=64,K=3 'SAME' — single persistent kernel
// with PER-ROW READY FLAGS (no global barrier, no per-step launches).
// Evidence R5-R9: ~26us/step floor invariant to M, blocks/CU, B-traffic,
// barriers, split-K -> the invariant is 16 stream-serialized dispatches
// (drain+launch+ramp ~10-14us each). R3's persistent attempt failed on a
// 512-contender single-cacheline RMW barrier, not on persistence itself.
// Here: block owns (b,y) row for all 16 steps; sync = 2 acquire spins on
// neighbor flags (monotonic, no RMW) + release flag store. Flag protocol
// bounds neighbor skew to 1 step (staging for t+2 needs neighbor flag t+2,
// set only after neighbor consumed h(t)) -> ping-pong h buffers are safe.
// Deadlock-free: 512 blocks <= residency (LDS 34.9KB -> 4/CU, lb(256,2)).
// c state stays in VGPRs for all 16 steps (no cbuf). Own h center row is
// self-written to LDS; only rows y+-1 reload from global (L2, XCD-banded).

#define B_ 8
#define T_ 16
#define CIN_ 16
#define HID_ 64
#define H_ 64
#define W_ 64
#define HW_ (H_*W_)
#define CTOT_ 80
#define XS_ROW 66                   // 64 px + 2 halo
#define XS_CH 88                    // x16|h64|bias|7pad; 176B px stride
#define XS_SIZE (3*XS_ROW*XS_CH)    // 17424 hw
#define XS_ALLOC (XS_SIZE + 16)     // cc2 overread slack (zeroed once)
#define CSTRIDE_ (B_*HID_*HW_)      // 2097152
#define FLAG_STRIDE 16              // ints; one flag per 64B line

typedef __attribute__((ext_vector_type(8))) short short8;
typedef __attribute__((ext_vector_type(4))) float f32x4;

__device__ __forceinline__ unsigned short f2bf(float f){
    unsigned u = __float_as_uint(f);
    u = (u + 0x7FFFu + ((u >> 16) & 1u)) >> 16;   // RNE
    return (unsigned short)u;
}
__device__ __forceinline__ float sigm_(float v){ return 1.0f/(1.0f + __expf(-v)); }
__device__ __forceinline__ float tanh_(float v){ return 2.0f/(1.0f + __expf(-2.0f*v)) - 1.0f; }

// Wfrag: [tap 9][cc 3][ng 16] frags of 512 hw ([lane][j]).
// n = ng*16+(lane&15): g=n>>6, o=n&63; k-ch c = cc*32+(lane>>4)*8+j.
// c: 0..15 x, 16..79 h, 80 bias (center tap only), 81..95 zero.
__global__ void prep_wfrag(const float* __restrict__ Wf, const float* __restrict__ Wi,
                           const float* __restrict__ Wc, const float* __restrict__ Wo,
                           const float* __restrict__ bf, const float* __restrict__ bi,
                           const float* __restrict__ bc, const float* __restrict__ bo,
                           unsigned short* __restrict__ Wfrag){
    int idx = blockIdx.x*256 + threadIdx.x;          // 864*256 = 221184 exact
    int j    = idx & 7;
    int lane = (idx >> 3) & 63;
    int frag = idx >> 9;
    int ng = frag & 15;
    int tc = frag >> 4;
    int cc = tc % 3, tap = tc / 3;
    int n = ng*16 + (lane & 15);
    int g = n >> 6, o = n & 63;
    int c = cc*32 + ((lane >> 4) << 3) + j;
    int ky = tap / 3, kx = tap % 3;
    float v = 0.0f;
    if (c < CTOT_){
        if (g == 0)      v = Wf[((o*CTOT_ + c)*3 + ky)*3 + kx];
        else if (g == 1) v = Wi[((o*CTOT_ + c)*3 + ky)*3 + kx];
        else if (g == 2) v = Wc[((o*CTOT_ + c)*3 + ky)*3 + kx];
        else             v = (tap == 4) ? Wo[o*CTOT_ + c] : 0.0f;
    } else if (c == CTOT_ && tap == 4){              // bias channel
        v = (g==0) ? bf[o] : (g==1) ? bi[o] : (g==2) ? bc[o] : bo[o];
    }
    Wfrag[idx] = f2bf(v);
}

// x[b][t][c][y][px] fp32 -> xbf[b][t][y][px][c16] bf16
__global__ void prep_xbf(const float* __restrict__ x, unsigned short* __restrict__ xbf){
    int idx = blockIdx.x*256 + threadIdx.x;          // 524288 = (b,t,y,px) flat
    int px = idx & 63;
    int y  = (idx >> 6) & 63;
    int bt = idx >> 12;
    const float* src = x + (size_t)bt*CIN_*HW_ + y*W_ + px;
    unsigned short tmp[16];
    #pragma unroll
    for (int c = 0; c < 16; ++c) tmp[c] = f2bf(src[(size_t)c*HW_]);
    uint4* dst = (uint4*)(xbf + (size_t)idx*16);
    dst[0] = *(uint4*)(tmp);
    dst[1] = *(uint4*)(tmp + 8);
}

__global__ __launch_bounds__(256, 2) void lstm_all(
    const unsigned short* __restrict__ xbf,
    const unsigned short* __restrict__ Wfrag,
    unsigned short* __restrict__ hA,     // h(even t) bf16 [b][y][px][o]
    unsigned short* __restrict__ hB,     // h(odd t)
    int* __restrict__ flags,             // [b*64+y]*FLAG_STRIDE, monotonic step counter
    float* __restrict__ out)             // [h|c] NCHW fp32
{
    __shared__ __align__(16) unsigned short Xs[XS_ALLOC];
    const int id   = blockIdx.x;
    // XCD swizzle: id&7 -> XCD; XCD k owns rows [8k,8k+8) -> y+-1 neighbor
    // flags/h are same-XCD-L2 except at band edges (1/8 of pairs).
    const int xcd  = id & 7;
    const int jj   = id >> 3;
    const int y    = xcd*8 + (jj & 7);
    const int b    = jj >> 3;
    const int tid  = threadIdx.x;
    const int lane = tid & 63;
    const int w    = tid >> 6;
    const int l15  = lane & 15;
    const int q    = lane >> 4;

    uint4 z4; z4.x=z4.y=z4.z=z4.w=0u;

    // ---- one-time: zero whole tile (h=0 for t=0, halos, pad ch, slack)
    for (int i = tid; i < XS_ALLOC/8; i += 256) ((uint4*)Xs)[i] = z4;
    __syncthreads();
    // ---- one-time: bias channel 80 = 1.0 (never overwritten afterwards)
    for (int i = tid; i < 3*XS_ROW; i += 256)
        Xs[((i/XS_ROW)*XS_ROW + (i%XS_ROW))*XS_CH + CTOT_] = 0x3F80;

    const int o = w*16 + l15;
    float creg[4][4] = {{0,0,0,0},{0,0,0,0},{0,0,0,0},{0,0,0,0}};

    for (int t = 0; t < T_; ++t){
        // ---- wait for neighbors' h(t), then acquire
        if (t > 0){
            if (tid == 0 && y > 0){
                const int* fp = flags + (((b<<6) | (y-1)) * FLAG_STRIDE);
                while (__hip_atomic_load(fp, __ATOMIC_ACQUIRE, __HIP_MEMORY_SCOPE_AGENT) < t)
                    __builtin_amdgcn_s_sleep(2);
            }
            if (tid == 1 && y < H_-1){
                const int* fp = flags + (((b<<6) | (y+1)) * FLAG_STRIDE);
                while (__hip_atomic_load(fp, __ATOMIC_ACQUIRE, __HIP_MEMORY_SCOPE_AGENT) < t)
                    __builtin_amdgcn_s_sleep(2);
            }
            __syncthreads();
            __threadfence();                         // acquire: invalidate stale lines
            // stage h(t) rows 0 and 2 (center row self-written at t-1 epilogue)
            const unsigned short* hin = (t & 1) ? hB : hA;
            for (int i = tid; i < 1056; i += 256){
                const int row = (i >= 528) ? 2 : 0;
                const int rem = i - ((i >= 528) ? 528 : 0);
                const int px = rem >> 3, ch8 = rem & 7;
                const int yy = y + row - 1, pxg = px - 1;
                uint4 v = z4;
                if (yy >= 0 && yy < H_ && pxg >= 0 && pxg < W_)
                    v = *(const uint4*)(hin + ((((size_t)b*H_ + yy)*W_ + pxg)*HID_ + ch8*8));
                *(uint4*)(Xs + (row*XS_ROW + px)*XS_CH + CIN_ + ch8*8) = v;
            }
        }
        // ---- stage x(t): 3 rows x 66 px x 2 ch8 = 396 uint4 (zeros on OOB)
        for (int i = tid; i < 396; i += 256){
            const int row = i/132, rem = i - row*132;
            const int px = rem >> 1, ch8 = rem & 1;
            const int yy = y + row - 1, pxg = px - 1;
            uint4 v = z4;
            if (yy >= 0 && yy < H_ && pxg >= 0 && pxg < W_)
                v = *(const uint4*)(xbf + ((((size_t)(b*T_ + t)*H_ + yy)*W_ + pxg)*16 + ch8*8));
            *(uint4*)(Xs + (row*XS_ROW + px)*XS_CH + ch8*8) = v;
        }
        __syncthreads();

        // ---- K-loop: 3 cc x 9 taps, A from LDS at body top, B depth-1 prefetch
        f32x4 acc[4][4];
        #pragma unroll
        for (int g = 0; g < 4; ++g)
            #pragma unroll
            for (int mf = 0; mf < 4; ++mf) acc[g][mf] = (f32x4)0.0f;

        short8 bC[3], bO;
        {   // preload B(cc=0, tap=0)
            const unsigned short* bp = Wfrag + ((size_t)w << 9) + lane*8;
            #pragma unroll
            for (int g = 0; g < 3; ++g) bC[g] = *(const short8*)(bp + ((size_t)(g*4) << 9));
        }
        #pragma unroll 1
        for (int cc = 0; cc < 3; ++cc){
            #pragma unroll
            for (int tap = 0; tap < 9; ++tap){
                const int ky = tap/3, kx = tap%3;
                short8 a[4];
                const unsigned short* ap =
                    Xs + (size_t)(ky*XS_ROW + l15 + kx)*XS_CH + cc*32 + q*8;
                #pragma unroll
                for (int mf = 0; mf < 4; ++mf) a[mf] = *(const short8*)(ap + (size_t)(mf*16)*XS_CH);
                short8 bN[3];
                const int nt = (tap == 8) ? 0 : tap + 1;
                const int nc = (tap == 8) ? cc + 1 : cc;
                if (nc < 3){
                    const unsigned short* bp =
                        Wfrag + ((size_t)((nt*3 + nc)*16 + w) << 9) + lane*8;
                    #pragma unroll
                    for (int g = 0; g < 3; ++g) bN[g] = *(const short8*)(bp + ((size_t)(g*4) << 9));
                }
                if (tap == 3)
                    bO = *(const short8*)(Wfrag + ((size_t)((4*3 + cc)*16 + 12 + w) << 9) + lane*8);
                if (tap == 4){
                    #pragma unroll
                    for (int mf = 0; mf < 4; ++mf)
                        acc[3][mf] = __builtin_amdgcn_mfma_f32_16x16x32_bf16(a[mf], bO, acc[3][mf], 0,0,0);
                }
                #pragma unroll
                for (int g = 0; g < 3; ++g)
                    #pragma unroll
                    for (int mf = 0; mf < 4; ++mf)
                        acc[g][mf] = __builtin_amdgcn_mfma_f32_16x16x32_bf16(a[mf], bC[g], acc[g][mf], 0,0,0);
                if (nc < 3){ bC[0]=bN[0]; bC[1]=bN[1]; bC[2]=bN[2]; }
            }
        }
        __syncthreads();         // tile dead: safe to overwrite center-row h in LDS

        // ---- epilogue: gates; c stays in VGPRs; h(t+1) -> global + own LDS row
        if (t < T_-1){
            unsigned short* hout = ((t+1) & 1) ? hB : hA;
            #pragma unroll
            for (int mf = 0; mf < 4; ++mf){
                #pragma unroll
                for (int r = 0; r < 4; ++r){
                    const int m = mf*16 + q*4 + r;
                    const float fv = sigm_(acc[0][mf][r]);
                    const float iv = sigm_(acc[1][mf][r]);
                    const float gv = tanh_(acc[2][mf][r]);
                    const float ov = sigm_(acc[3][mf][r]);
                    const float cn = creg[mf][r]*fv + iv*gv;
                    creg[mf][r] = cn;
                    const unsigned short hv = f2bf(tanh_(cn)*ov);
                    hout[(((size_t)b*H_ + y)*W_ + m)*HID_ + o] = hv;
                    Xs[(XS_ROW + m + 1)*XS_CH + CIN_ + o] = hv;   // center row, t+1
                }
            }
            __threadfence();     // release: drain h stores to coherence point
            __syncthreads();
            if (tid == 0)
                __hip_atomic_store(flags + (((b<<6) | y) * FLAG_STRIDE), t+1,
                                   __ATOMIC_RELEASE, __HIP_MEMORY_SCOPE_AGENT);
        } else {
            #pragma unroll
            for (int mf = 0; mf < 4; ++mf){
                #pragma unroll
                for (int r = 0; r < 4; ++r){
                    const int m = mf*16 + q*4 + r;
                    const float fv = sigm_(acc[0][mf][r]);
                    const float iv = sigm_(acc[1][mf][r]);
                    const float gv = tanh_(acc[2][mf][r]);
                    const float ov = sigm_(acc[3][mf][r]);
                    const float cn = creg[mf][r]*fv + iv*gv;
                    const float hn = tanh_(cn)*ov;
                    const size_t oidx = ((((size_t)(b*HID_ + o))*H_ + y)*W_ + m);
                    out[oidx] = hn;
                    out[CSTRIDE_ + oidx] = cn;
                }
            }
        }
    }
}

extern "C" void kernel_launch(void* const* d_in, const int* in_sizes, int n_in,
                              void* d_out, int out_size, void* d_ws, size_t ws_size,
                              hipStream_t stream){
    const float* x  = (const float*)d_in[0];
    const float* Wf = (const float*)d_in[1];
    const float* bf = (const float*)d_in[2];
    const float* Wi = (const float*)d_in[3];
    const float* bi = (const float*)d_in[4];
    const float* Wc = (const float*)d_in[5];
    const float* bc = (const float*)d_in[6];
    const float* Wo = (const float*)d_in[7];
    const float* bo = (const float*)d_in[8];

    // ws: Wfrag 442368 | xbf 16777216 | hA 4194304 | hB 4194304 | flags 32768
    unsigned short* Wfrag = (unsigned short*)d_ws;
    unsigned short* xbf   = (unsigned short*)((char*)d_ws + 442368);
    unsigned short* hA    = (unsigned short*)((char*)d_ws + 442368 + 16777216);
    unsigned short* hB    = hA + CSTRIDE_;
    int*            flags = (int*)((char*)d_ws + 442368 + 16777216 + 2*4194304);

    hipMemsetAsync(flags, 0, 512*FLAG_STRIDE*sizeof(int), stream);
    prep_wfrag<<<dim3(864), dim3(256), 0, stream>>>(Wf, Wi, Wc, Wo, bf, bi, bc, bo, Wfrag);
    prep_xbf<<<dim3(2048), dim3(256), 0, stream>>>(x, xbf);

    lstm_all<<<dim3(512), dim3(256), 0, stream>>>(
        xbf, Wfrag, hA, hB, flags, (float*)d_out);
}